// Round 1
// baseline (4840.233 us; speedup 1.0000x reference)
//
#include <hip/hip_runtime.h>

#define EPSV 1e-4f

__device__ __forceinline__ float bperm(int addr4, float v) {
  return __int_as_float(__builtin_amdgcn_ds_bpermute(addr4, __float_as_int(v)));
}

// zero-instruction compiler memory fence: LDS hazards here are all same-wave
// (per-group scratch); HW processes a wave's DS ops in order, we only need to
// stop the compiler from reordering across the phase boundary.
__device__ __forceinline__ void wave_fence() { asm volatile("" ::: "memory"); }

// variable-index read of a register array via cndmask chain (stays in VGPRs)
template<int N>
__device__ __forceinline__ float selN(const float (&a)[N], int idx) {
  float r = a[0];
#pragma unroll
  for (int k = 1; k < N; ++k) r = (idx == k) ? a[k] : r;
  return r;
}

// Parallel cyclic Jacobi, circle-method tournament with fixed physical pairs
// (i, N-1-i). Lane l (group-local) holds column l of A and row l of V in
// registers. Round body is round-invariant; after each full sweep (N-1
// rounds) labels coincide with slots again.
// Rotation params travel as the tangent tt only (1 bperm/pair, was 2); every
// lane -- including the pair owners' own column update -- derives
// c = rsq(tt^2+1), s = tt*c with the identical instruction sequence, so all
// lanes use bit-identical rotations.
template<int N>
__device__ void jacobi_eig(float (&a)[N], float (&v)[N], int l, int base4,
                           bool laneValid, float tolsq, int maxSweeps)
{
  constexpr int NH = N / 2;
  const int partner = N - 1 - l;
  const int pslot = (l < NH) ? l : partner;
  const int qslot = N - 1 - pslot;
  const int p4 = base4 + 4 * pslot;
  const int q4 = base4 + 4 * qslot;
  const int pr4 = base4 + 4 * partner;
  const int srcl = (l == 0) ? 0 : ((l == 1) ? (N - 1) : (l - 1));
  const int src4 = base4 + 4 * srcl;
  const bool isP = (l < NH);

  float dval = selN<N>(a, l);   // own diagonal, maintained incrementally
  int sweep = 0;
  while (true) {
    float offAcc = 0.0f;
    for (int r = 0; r < N - 1; ++r) {
      float anti = selN<N>(a, partner);       // A[partner][l] == A[l][partner]
      float app = bperm(p4, dval);            // consistent params on both lanes
      float aqq = bperm(q4, dval);
      float apq = bperm(p4, anti);

      float absq = fabsf(apq);
      bool ok = absq > 1e-28f;
      float apqs = ok ? apq : 1.0f;
      float theta = 0.5f * (aqq - app) / apqs;
      float tt = 1.0f / (fabsf(theta) + sqrtf(theta * theta + 1.0f));
      tt = (theta < 0.0f) ? -tt : tt;
      tt = ok ? tt : 0.0f;
      float c = __builtin_amdgcn_rsqf(tt * tt + 1.0f);  // same derivation as
      float s = tt * c;                                 // remote lanes use
      offAcc += laneValid ? apq * apq : 0.0f;  // == ||offdiag||_F^2 per sweep

      // column update: A <- A*G (my column combines with partner's)
      float seff = isP ? -s : s;
#pragma unroll
      for (int k = 0; k < N; ++k) {
        float pc = bperm(pr4, a[k]);
        a[k] = c * a[k] + seff * pc;
      }
      // row update A <- G^T*A, plus V <- V*G (V rows: shuffle-free).
      // Only tt travels; c,s rederived identically on every lane.
#pragma unroll
      for (int i = 0; i < NH; ++i) {
        float ti = bperm(base4 + 4 * i, tt);
        float ci = __builtin_amdgcn_rsqf(ti * ti + 1.0f);
        float si = ti * ci;
        float x = a[i], y = a[N - 1 - i];
        a[i]         = ci * x - si * y;
        a[N - 1 - i] = si * x + ci * y;
        float xv = v[i], yv = v[N - 1 - i];
        v[i]         = ci * xv - si * yv;
        v[N - 1 - i] = si * xv + ci * yv;
      }
      float dnew = isP ? (app - tt * apq) : (aqq + tt * apq);

      // tournament permutation: slot0 fixed, tail rotated (same sigma for
      // rows, columns, and V's column labels)
      float tmp[N];
#pragma unroll
      for (int k = 0; k < N; ++k) tmp[k] = bperm(src4, a[k]);
      a[0] = tmp[0];
      a[1] = tmp[N - 1];
#pragma unroll
      for (int k = 2; k < N; ++k) a[k] = tmp[k - 1];
      float xl = v[N - 1];
#pragma unroll
      for (int k = N - 1; k >= 2; --k) v[k] = v[k - 1];
      v[1] = xl;
      dval = bperm(src4, dnew);
    }
    ++sweep;
#pragma unroll
    for (int m = 1; m < 64; m <<= 1) offAcc += __shfl_xor(offAcc, m);
    if (sweep >= maxSweeps || offAcc < tolsq) break;   // wave-uniform
  }
}

// block = 256 threads = 4 waves; each wave owns 3 matrices (20 lanes each,
// lanes 60..63 are harmless shadows of group 2: they never write LDS/global
// and are never bpermute sources for real lanes).
// X is NOT staged in LDS: each group streams its own matrix with broadcast
// float4 loads (all 20 lanes same address -> one request per instruction).
// LDS = per-matrix 420-float scratch only => 20.2 KB/block => 5 blocks/CU
// at waves_per_eu=5 (was 3 blocks at 50 KB).
__global__ __launch_bounds__(256, 5)
void spdnet_kernel(const float* __restrict__ X, const float* __restrict__ W1g,
                   const float* __restrict__ W2g, float* __restrict__ out,
                   int nBatch)
{
  __shared__ __align__(16) float sS[12 * 420];

  const int tid = threadIdx.x;
  const int wave = tid >> 6;
  const int lane = tid & 63;
  const int grp = lane / 20;          // 0..3 (3 = shadow)
  const int l = lane - grp * 20;      // 0..19
  const int g3 = (grp < 3) ? grp : 2;
  const bool activeG = (grp < 3);
  const int wstart = blockIdx.x * 12 + wave * 3;
  const int bm = wstart + g3;
  const bool valid = activeG && (bm < nBatch);
  const int base4 = g3 * 80;          // group base lane * 4 bytes
  float* Sm = sS + (wave * 3 + g3) * 420;   // this group's scratch region

  // W1 row l from global (float2: rows are only 8B-aligned)
  float w1r[30];
  {
    const float2* wr = (const float2*)(W1g + l * 30);
#pragma unroll
    for (int k2 = 0; k2 < 15; ++k2) {
      float2 q = wr[k2];
      w1r[2 * k2] = q.x; w1r[2 * k2 + 1] = q.y;
    }
  }

  // tcol = X * w1_row(l), streamed from global (matrix base is 16B-aligned:
  // 900 floats = 3600 B). Static (r,k) decomposition keeps tcol in VGPRs.
  const int bmc = (bm < nBatch) ? bm : (nBatch - 1);   // clamp: stay in-bounds
  const float4* Xm = (const float4*)(X + (size_t)bmc * 900);
  float tcol[30];
#pragma unroll
  for (int r = 0; r < 30; ++r) tcol[r] = 0.0f;
#pragma unroll
  for (int q = 0; q < 225; ++q) {
    float4 x4 = Xm[q];
    tcol[(4 * q + 0) / 30] += x4.x * w1r[(4 * q + 0) % 30];
    tcol[(4 * q + 1) / 30] += x4.y * w1r[(4 * q + 1) % 30];
    tcol[(4 * q + 2) / 30] += x4.z * w1r[(4 * q + 2) % 30];
    tcol[(4 * q + 3) / 30] += x4.w * w1r[(4 * q + 3) % 30];
  }

  // z = W1 * tcol = column l of Z = W1 X W1^T. W1 loads are wave-uniform
  // (scalarizable); off the DS pipe on purpose.
  float z[20];
#pragma unroll
  for (int i = 0; i < 20; ++i) z[i] = 0.0f;
  {
    const float4* W14 = (const float4*)W1g;
#pragma unroll
    for (int q = 0; q < 150; ++q) {
      float4 w4 = W14[q];
      z[(4 * q + 0) / 30] += w4.x * tcol[(4 * q + 0) % 30];
      z[(4 * q + 1) / 30] += w4.y * tcol[(4 * q + 1) % 30];
      z[(4 * q + 2) / 30] += w4.z * tcol[(4 * q + 2) % 30];
      z[(4 * q + 3) / 30] += w4.w * tcol[(4 * q + 3) % 30];
    }
  }

  // symmetrize via in-wave LDS transpose (stride 21: 20 lanes hit 20 distinct
  // banks): a[i] = 0.5*(Z[i][l] + Z[l][i]) + eps I. Bitwise symmetric since
  // fp add commutes.
  if (activeG) {
#pragma unroll
    for (int k = 0; k < 20; ++k) Sm[k * 21 + l] = z[k];   // write column l
  }
  wave_fence();
  float a[20], v[20];
#pragma unroll
  for (int i = 0; i < 20; ++i) {
    float zt = Sm[l * 21 + i];                            // read row l
    a[i] = 0.5f * (z[i] + zt) + ((i == l) ? EPSV : 0.0f);
    v[i] = (i == l) ? 1.0f : 0.0f;
  }

  jacobi_eig<20>(a, v, l, base4, valid, 2.0e-9f, 12);

  float lam1 = selN<20>(a, l);
  float gs = sqrtf(fmaxf(lam1, EPSV));

  // write V rows; then each lane grabs eigenvector column l
  if (activeG) {
#pragma unroll
    for (int k = 0; k < 20; ++k) Sm[l * 21 + k] = v[k];
  }
  wave_fence();
  float vcol[20];
#pragma unroll
  for (int r = 0; r < 20; ++r) vcol[r] = Sm[r * 21 + l];

  // b = W2 * v_l ; W2 streamed wave-uniform from global
  float b[15];
#pragma unroll
  for (int i = 0; i < 15; ++i) b[i] = 0.0f;
  {
    const float4* W24 = (const float4*)W2g;
#pragma unroll
    for (int q = 0; q < 75; ++q) {
      float4 w4 = W24[q];
      b[(4 * q + 0) / 20] += w4.x * vcol[(4 * q + 0) % 20];
      b[(4 * q + 1) / 20] += w4.y * vcol[(4 * q + 1) % 20];
      b[(4 * q + 2) / 20] += w4.z * vcol[(4 * q + 2) % 20];
      b[(4 * q + 3) / 20] += w4.w * vcol[(4 * q + 3) % 20];
    }
  }

  // Ut overlaps the (dead) V storage; fence orders the WAR (per-lane-disjoint
  // addresses, cross-lane overlap)
  wave_fence();
  float* Ut = Sm;                       // 15 x 20 (rows 16B-aligned)
  if (activeG) {
#pragma unroll
    for (int i = 0; i < 15; ++i) Ut[i * 20 + l] = gs * b[i];
  }
  wave_fence();

  // Y2 (padded to 16x16, dummy row/col 15 = 0): a2[r] = <Ut[r][:], Ut[l2][:]>
  const int l2 = l & 15;
  float myrow[20];
  {
    const float4* mr = (const float4*)(Ut + ((l2 < 15) ? l2 : 0) * 20);
    float msk = (l2 < 15) ? 1.0f : 0.0f;
#pragma unroll
    for (int r4 = 0; r4 < 5; ++r4) {
      float4 q = mr[r4];
      myrow[4 * r4]     = q.x * msk; myrow[4 * r4 + 1] = q.y * msk;
      myrow[4 * r4 + 2] = q.z * msk; myrow[4 * r4 + 3] = q.w * msk;
    }
  }
  float a2[16], v2[16];
  a2[15] = 0.0f;
#pragma unroll
  for (int r = 0; r < 15; ++r) {
    const float4* ur = (const float4*)(Ut + r * 20);
    float acc = 0.0f;
#pragma unroll
    for (int r4 = 0; r4 < 5; ++r4) {
      float4 q = ur[r4];
      acc += q.x * myrow[4 * r4] + q.y * myrow[4 * r4 + 1] +
             q.z * myrow[4 * r4 + 2] + q.w * myrow[4 * r4 + 3];
    }
    a2[r] = acc + ((r == l2) ? EPSV : 0.0f);
  }
#pragma unroll
  for (int k = 0; k < 16; ++k) v2[k] = (k == l2) ? 1.0f : 0.0f;

  jacobi_eig<16>(a2, v2, l2, base4, valid && (l < 16), 3.0e-10f, 12);

  float lam2 = selN<16>(a2, l2);
  float h = logf(fmaxf(lam2, EPSV));   // fused reeig+logeig: log(max(mu,eps))

  wave_fence();
  float* Wl = Sm;                       // 16 x 20 (Ut dead)
  float* hl = Sm + 400;                 // 16 (disjoint from Wl's 320)
  if (activeG && l < 16) {
#pragma unroll
    for (int k = 0; k < 16; ++k) Wl[l2 * 20 + k] = v2[k];
    hl[l2] = h;
  }
  wave_fence();

  // M[i][j] = sum_k h_k V2[i][k] V2[j][k]; lane j=l stores rows i<=j of triu
  if (valid && l < 15) {
    float wj[15], hw[15];
#pragma unroll
    for (int k = 0; k < 15; ++k) wj[k] = Wl[l * 20 + k];
#pragma unroll
    for (int k = 0; k < 15; ++k) hw[k] = hl[k] * wj[k];
    float* og = out + (size_t)bm * 120;
#pragma unroll
    for (int i = 0; i < 15; ++i) {
      const float* wr = Wl + i * 20;
      float acc = 0.0f;
#pragma unroll
      for (int k = 0; k < 15; ++k) acc += hw[k] * wr[k];
      if (i <= l) og[15 * i - (i * (i - 1)) / 2 + (l - i)] = acc;
    }
  }
}

extern "C" void kernel_launch(void* const* d_in, const int* in_sizes, int n_in,
                              void* d_out, int out_size, void* d_ws, size_t ws_size,
                              hipStream_t stream) {
  const float* X  = (const float*)d_in[0];
  const float* W1 = (const float*)d_in[1];
  const float* W2 = (const float*)d_in[2];
  float* out = (float*)d_out;
  int nBatch = in_sizes[0] / 900;
  int nBlocks = (nBatch + 11) / 12;   // 12 matrices per 256-thread block
  spdnet_kernel<<<nBlocks, 256, 0, stream>>>(X, W1, W2, out, nBatch);
}

// Round 4
// 4577.943 us; speedup vs baseline: 1.0573x; 1.0573x over previous
//
#include <hip/hip_runtime.h>

#define EPSV 1e-4f

__device__ __forceinline__ float bperm(int addr4, float v) {
  return __int_as_float(__builtin_amdgcn_ds_bpermute(addr4, __float_as_int(v)));
}

// zero-instruction compiler memory fence: LDS hazards here are all same-wave
// (per-group scratch); HW processes a wave's DS ops in order, we only need to
// stop the compiler from reordering across the phase boundary.
__device__ __forceinline__ void wave_fence() { asm volatile("" ::: "memory"); }

// variable-index read of a register array via cndmask chain (stays in VGPRs)
template<int N>
__device__ __forceinline__ float selN(const float (&a)[N], int idx) {
  float r = a[0];
#pragma unroll
  for (int k = 1; k < N; ++k) r = (idx == k) ? a[k] : r;
  return r;
}

// Parallel cyclic Jacobi, circle-method tournament with fixed physical pairs
// (i, N-1-i). Lane l (group-local) holds column l of A and row l of V in
// registers. Round body is round-invariant; after each full sweep (N-1
// rounds) labels coincide with slots again.
// Rotation params travel as the tangent tt only (1 bperm/pair); every lane
// derives c = rsq(tt^2+1), s = tt*c by the identical instruction sequence,
// so all lanes use bit-identical rotations.
template<int N>
__device__ void jacobi_eig(float (&a)[N], float (&v)[N], int l, int base4,
                           bool laneValid, float tolsq, int maxSweeps)
{
  constexpr int NH = N / 2;
  const int partner = N - 1 - l;
  const int pslot = (l < NH) ? l : partner;
  const int qslot = N - 1 - pslot;
  const int p4 = base4 + 4 * pslot;
  const int q4 = base4 + 4 * qslot;
  const int pr4 = base4 + 4 * partner;
  const int srcl = (l == 0) ? 0 : ((l == 1) ? (N - 1) : (l - 1));
  const int src4 = base4 + 4 * srcl;
  const bool isP = (l < NH);

  float dval = selN<N>(a, l);   // own diagonal, maintained incrementally
  int sweep = 0;
  while (true) {
    float offAcc = 0.0f;
    for (int r = 0; r < N - 1; ++r) {
      float anti = selN<N>(a, partner);       // A[partner][l] == A[l][partner]
      float app = bperm(p4, dval);            // consistent params on both lanes
      float aqq = bperm(q4, dval);
      float apq = bperm(p4, anti);

      float absq = fabsf(apq);
      bool ok = absq > 1e-28f;
      float apqs = ok ? apq : 1.0f;
      float theta = 0.5f * (aqq - app) / apqs;
      float tt = 1.0f / (fabsf(theta) + sqrtf(theta * theta + 1.0f));
      tt = (theta < 0.0f) ? -tt : tt;
      tt = ok ? tt : 0.0f;
      float c = __builtin_amdgcn_rsqf(tt * tt + 1.0f);  // same derivation on
      float s = tt * c;                                 // every lane
      offAcc += laneValid ? apq * apq : 0.0f;  // == ||offdiag||_F^2 per sweep

      // column update: A <- A*G (my column combines with partner's)
      float seff = isP ? -s : s;
#pragma unroll
      for (int k = 0; k < N; ++k) {
        float pc = bperm(pr4, a[k]);
        a[k] = c * a[k] + seff * pc;
      }
      // row update A <- G^T*A, plus V <- V*G (V rows: shuffle-free).
      // Only tt travels; c,s rederived identically on every lane.
#pragma unroll
      for (int i = 0; i < NH; ++i) {
        float ti = bperm(base4 + 4 * i, tt);
        float ci = __builtin_amdgcn_rsqf(ti * ti + 1.0f);
        float si = ti * ci;
        float x = a[i], y = a[N - 1 - i];
        a[i]         = ci * x - si * y;
        a[N - 1 - i] = si * x + ci * y;
        float xv = v[i], yv = v[N - 1 - i];
        v[i]         = ci * xv - si * yv;
        v[N - 1 - i] = si * xv + ci * yv;
      }
      float dnew = isP ? (app - tt * apq) : (aqq + tt * apq);

      // tournament permutation: slot0 fixed, tail rotated (same sigma for
      // rows, columns, and V's column labels)
      float tmp[N];
#pragma unroll
      for (int k = 0; k < N; ++k) tmp[k] = bperm(src4, a[k]);
      a[0] = tmp[0];
      a[1] = tmp[N - 1];
#pragma unroll
      for (int k = 2; k < N; ++k) a[k] = tmp[k - 1];
      float xl = v[N - 1];
#pragma unroll
      for (int k = N - 1; k >= 2; --k) v[k] = v[k - 1];
      v[1] = xl;
      dval = bperm(src4, dnew);
    }
    ++sweep;
#pragma unroll
    for (int m = 1; m < 64; m <<= 1) offAcc += __shfl_xor(offAcc, m);
    if (sweep >= maxSweeps || offAcc < tolsq) break;   // wave-uniform
  }
}

// block = 256 threads = 4 waves; each wave owns 3 matrices (20 lanes each,
// lanes 60..63 are harmless shadows of group 2: they never write LDS/global
// and are never bpermute sources for real lanes).
// X streams from global with broadcast float2 loads (all 20 lanes of a group
// read the same address -> one line per request). The two bimap GEMVs are
// FUSED into one rolled row-loop with a scalar accumulator so no 30-wide
// register array crosses a loop boundary: peak live set ~60 VGPRs, no chance
// of the scratch demotion that killed round 1 (VGPR=48, 10.5 GB scratch
// traffic). launch_bounds(256,4): cap 128 VGPRs -- spill-free headroom.
__global__ __launch_bounds__(256, 4)
void spdnet_kernel(const float* __restrict__ X, const float* __restrict__ W1g,
                   const float* __restrict__ W2g, float* __restrict__ out,
                   int nBatch)
{
  __shared__ __align__(16) float sS[12 * 420];
  __shared__ __align__(16) float sW1t[30 * 20];   // W1 transposed: [r][i]

  const int tid = threadIdx.x;
  const int wave = tid >> 6;
  const int lane = tid & 63;
  const int grp = lane / 20;          // 0..3 (3 = shadow)
  const int l = lane - grp * 20;      // 0..19
  const int g3 = (grp < 3) ? grp : 2;
  const bool activeG = (grp < 3);
  const int wstart = blockIdx.x * 12 + wave * 3;
  const int bm = wstart + g3;
  const bool valid = activeG && (bm < nBatch);
  const int base4 = g3 * 80;          // group base lane * 4 bytes
  float* Sm = sS + (wave * 3 + g3) * 420;   // this group's scratch region

  // stage W1^T (2.4 KB): coalesced global read, scattered LDS write
  for (int t0 = tid; t0 < 600; t0 += 256) {
    int i = t0 / 30, r = t0 - i * 30;
    sW1t[r * 20 + i] = W1g[t0];
  }

  // W1 row l from global (float2: rows are only 8B-aligned)
  float w1r[30];
  {
    const float2* wr = (const float2*)(W1g + l * 30);
#pragma unroll
    for (int k2 = 0; k2 < 15; ++k2) {
      float2 q = wr[k2];
      w1r[2 * k2] = q.x; w1r[2 * k2 + 1] = q.y;
    }
  }
  __syncthreads();   // sW1t ready (only block-wide barrier in the kernel)

  // z[i] = (W1 X W1^T)[i][l] = sum_r W1t[r][i] * (X[r,:] . w1r)
  // Outer loop rolled (r only forms addresses); inner loops unrolled with
  // static register indices. Two-way split accumulator halves the FMA chain.
  const int bmc = (bm < nBatch) ? bm : (nBatch - 1);   // clamp: stay in-bounds
  const float* Xm = X + (size_t)bmc * 900;
  float z[20];
#pragma unroll
  for (int i = 0; i < 20; ++i) z[i] = 0.0f;
  for (int r = 0; r < 30; ++r) {
    const float2* xr = (const float2*)(Xm + r * 30);   // 8B-aligned always
    float t0 = 0.0f, t1 = 0.0f;
#pragma unroll
    for (int k2 = 0; k2 < 15; ++k2) {
      float2 q = xr[k2];
      t0 = fmaf(q.x, w1r[2 * k2], t0);
      t1 = fmaf(q.y, w1r[2 * k2 + 1], t1);
    }
    float t = t0 + t1;
    const float* wc = sW1t + r * 20;    // broadcast reads (uniform address)
#pragma unroll
    for (int i = 0; i < 20; ++i) z[i] = fmaf(wc[i], t, z[i]);
  }

  // symmetrize via in-wave LDS transpose (stride 21: 20 lanes hit 20 distinct
  // banks): a[i] = 0.5*(Z[i][l] + Z[l][i]) + eps I. Bitwise symmetric since
  // fp add commutes.
  if (activeG) {
#pragma unroll
    for (int k = 0; k < 20; ++k) Sm[k * 21 + l] = z[k];   // write column l
  }
  wave_fence();
  float a[20], v[20];
#pragma unroll
  for (int i = 0; i < 20; ++i) {
    float zt = Sm[l * 21 + i];                            // read row l
    a[i] = 0.5f * (z[i] + zt) + ((i == l) ? EPSV : 0.0f);
    v[i] = (i == l) ? 1.0f : 0.0f;
  }

  jacobi_eig<20>(a, v, l, base4, valid, 2.0e-9f, 12);

  float lam1 = selN<20>(a, l);
  float gs = sqrtf(fmaxf(lam1, EPSV));

  // write V rows; then each lane grabs eigenvector column l
  if (activeG) {
#pragma unroll
    for (int k = 0; k < 20; ++k) Sm[l * 21 + k] = v[k];
  }
  wave_fence();
  float vcol[20];
#pragma unroll
  for (int r = 0; r < 20; ++r) vcol[r] = Sm[r * 21 + l];

  // b = W2 * v_l ; per-row float4 (rows are 80 B = 16B-aligned), static vcol
  // indices; uniform addresses -> L1-resident after first wave
  float b[15];
#pragma unroll
  for (int i = 0; i < 15; ++i) {
    const float4* w2r = (const float4*)(W2g + i * 20);
    float acc = 0.0f;
#pragma unroll
    for (int r4 = 0; r4 < 5; ++r4) {
      float4 q = w2r[r4];
      acc += q.x * vcol[4 * r4] + q.y * vcol[4 * r4 + 1] +
             q.z * vcol[4 * r4 + 2] + q.w * vcol[4 * r4 + 3];
    }
    b[i] = acc;
  }

  // Ut overlaps the (dead) V storage; fence orders the WAR (per-lane-disjoint
  // addresses, cross-lane overlap)
  wave_fence();
  float* Ut = Sm;                       // 15 x 20 (rows 16B-aligned)
  if (activeG) {
#pragma unroll
    for (int i = 0; i < 15; ++i) Ut[i * 20 + l] = gs * b[i];
  }
  wave_fence();

  // Y2 (padded to 16x16, dummy row/col 15 = 0): a2[r] = <Ut[r][:], Ut[l2][:]>
  const int l2 = l & 15;
  float myrow[20];
  {
    const float4* mr = (const float4*)(Ut + ((l2 < 15) ? l2 : 0) * 20);
    float msk = (l2 < 15) ? 1.0f : 0.0f;
#pragma unroll
    for (int r4 = 0; r4 < 5; ++r4) {
      float4 q = mr[r4];
      myrow[4 * r4]     = q.x * msk; myrow[4 * r4 + 1] = q.y * msk;
      myrow[4 * r4 + 2] = q.z * msk; myrow[4 * r4 + 3] = q.w * msk;
    }
  }
  float a2[16], v2[16];
  a2[15] = 0.0f;
#pragma unroll
  for (int r = 0; r < 15; ++r) {
    const float4* ur = (const float4*)(Ut + r * 20);
    float acc = 0.0f;
#pragma unroll
    for (int r4 = 0; r4 < 5; ++r4) {
      float4 q = ur[r4];
      acc += q.x * myrow[4 * r4] + q.y * myrow[4 * r4 + 1] +
             q.z * myrow[4 * r4 + 2] + q.w * myrow[4 * r4 + 3];
    }
    a2[r] = acc + ((r == l2) ? EPSV : 0.0f);
  }
#pragma unroll
  for (int k = 0; k < 16; ++k) v2[k] = (k == l2) ? 1.0f : 0.0f;

  jacobi_eig<16>(a2, v2, l2, base4, valid && (l < 16), 3.0e-10f, 12);

  float lam2 = selN<16>(a2, l2);
  float h = logf(fmaxf(lam2, EPSV));   // fused reeig+logeig: log(max(mu,eps))

  wave_fence();
  float* Wl = Sm;                       // 16 x 20 (Ut dead)
  float* hl = Sm + 400;                 // 16 (disjoint from Wl's 320)
  if (activeG && l < 16) {
#pragma unroll
    for (int k = 0; k < 16; ++k) Wl[l2 * 20 + k] = v2[k];
    hl[l2] = h;
  }
  wave_fence();

  // M[i][j] = sum_k h_k V2[i][k] V2[j][k]; lane j=l stores rows i<=j of triu
  if (valid && l < 15) {
    float wj[15], hw[15];
#pragma unroll
    for (int k = 0; k < 15; ++k) wj[k] = Wl[l * 20 + k];
#pragma unroll
    for (int k = 0; k < 15; ++k) hw[k] = hl[k] * wj[k];
    float* og = out + (size_t)bm * 120;
#pragma unroll
    for (int i = 0; i < 15; ++i) {
      const float* wr = Wl + i * 20;
      float acc = 0.0f;
#pragma unroll
      for (int k = 0; k < 15; ++k) acc += hw[k] * wr[k];
      if (i <= l) og[15 * i - (i * (i - 1)) / 2 + (l - i)] = acc;
    }
  }
}

extern "C" void kernel_launch(void* const* d_in, const int* in_sizes, int n_in,
                              void* d_out, int out_size, void* d_ws, size_t ws_size,
                              hipStream_t stream) {
  const float* X  = (const float*)d_in[0];
  const float* W1 = (const float*)d_in[1];
  const float* W2 = (const float*)d_in[2];
  float* out = (float*)d_out;
  int nBatch = in_sizes[0] / 900;
  int nBlocks = (nBatch + 11) / 12;   // 12 matrices per 256-thread block
  spdnet_kernel<<<nBlocks, 256, 0, stream>>>(X, W1, W2, out, nBatch);
}

// Round 5
// 4392.811 us; speedup vs baseline: 1.1019x; 1.0421x over previous
//
#include <hip/hip_runtime.h>

#define EPSV 1e-4f

__device__ __forceinline__ float bperm(int addr4, float v) {
  return __int_as_float(__builtin_amdgcn_ds_bpermute(addr4, __float_as_int(v)));
}

// zero-instruction compiler memory fence: LDS hazards here are all same-wave
// (per-group scratch); HW processes a wave's DS ops in order, we only need to
// stop the compiler from reordering across the phase boundary.
__device__ __forceinline__ void wave_fence() { asm volatile("" ::: "memory"); }

// variable-index read of a register array via cndmask chain (stays in VGPRs)
template<int N>
__device__ __forceinline__ float selN(const float (&a)[N], int idx) {
  float r = a[0];
#pragma unroll
  for (int k = 1; k < N; ++k) r = (idx == k) ? a[k] : r;
  return r;
}

// Parallel cyclic Jacobi, circle-method tournament with fixed physical pairs
// (i, N-1-i). Lane l (group-local) holds column l of A and row l of V in
// registers. Round body is round-invariant; after each full sweep (N-1
// rounds) labels coincide with slots again.
// Rotation params travel as the tangent tt only (1 bperm/pair); every lane
// derives c = rsq(tt^2+1), s = tt*c by the identical instruction sequence,
// so all lanes use bit-identical rotations.
// Tournament permutation is IN-PLACE (single temp, descending chain) -- the
// old tmp[N] doubled a[]'s footprint at the peak-pressure point and caused
// per-round spills at VGPR<=80 (rounds 0/1/4: 2-10 GB scratch writes).
template<int N>
__device__ void jacobi_eig(float (&a)[N], float (&v)[N], int l, int base4,
                           bool laneValid, float tolsq, int maxSweeps)
{
  constexpr int NH = N / 2;
  const int partner = N - 1 - l;
  const int pslot = (l < NH) ? l : partner;
  const int qslot = N - 1 - pslot;
  const int p4 = base4 + 4 * pslot;
  const int q4 = base4 + 4 * qslot;
  const int pr4 = base4 + 4 * partner;
  const int srcl = (l == 0) ? 0 : ((l == 1) ? (N - 1) : (l - 1));
  const int src4 = base4 + 4 * srcl;
  const bool isP = (l < NH);

  float dval = selN<N>(a, l);   // own diagonal, maintained incrementally
  int sweep = 0;
  while (true) {
    float offAcc = 0.0f;
    for (int r = 0; r < N - 1; ++r) {
      float anti = selN<N>(a, partner);       // A[partner][l] == A[l][partner]
      float app = bperm(p4, dval);            // consistent params on both lanes
      float aqq = bperm(q4, dval);
      float apq = bperm(p4, anti);

      float absq = fabsf(apq);
      bool ok = absq > 1e-28f;
      float apqs = ok ? apq : 1.0f;
      float theta = 0.5f * (aqq - app) / apqs;
      float tt = 1.0f / (fabsf(theta) + sqrtf(theta * theta + 1.0f));
      tt = (theta < 0.0f) ? -tt : tt;
      tt = ok ? tt : 0.0f;
      float c = __builtin_amdgcn_rsqf(tt * tt + 1.0f);  // same derivation on
      float s = tt * c;                                 // every lane
      offAcc += laneValid ? apq * apq : 0.0f;  // == ||offdiag||_F^2 per sweep

      // column update: A <- A*G (my column combines with partner's)
      float seff = isP ? -s : s;
#pragma unroll
      for (int k = 0; k < N; ++k) {
        float pc = bperm(pr4, a[k]);
        a[k] = c * a[k] + seff * pc;
      }
      // row update A <- G^T*A, plus V <- V*G (V rows: shuffle-free).
      // Only tt travels; c,s rederived identically on every lane.
#pragma unroll
      for (int i = 0; i < NH; ++i) {
        float ti = bperm(base4 + 4 * i, tt);
        float ci = __builtin_amdgcn_rsqf(ti * ti + 1.0f);
        float si = ti * ci;
        float x = a[i], y = a[N - 1 - i];
        a[i]         = ci * x - si * y;
        a[N - 1 - i] = si * x + ci * y;
        float xv = v[i], yv = v[N - 1 - i];
        v[i]         = ci * xv - si * yv;
        v[N - 1 - i] = si * xv + ci * yv;
      }
      float dnew = isP ? (app - tt * apq) : (aqq + tt * apq);

      // tournament permutation, IN-PLACE: slot0 fixed, tail rotated (same
      // sigma for rows, columns, and V's column labels).
      // new a[k] = S(old a[k-1]) for k>=2, new a[1] = S(old a[N-1]),
      // new a[0] = S(old a[0]); descending k reads a[k-1] before writing it.
      {
        float t1 = bperm(src4, a[N - 1]);
#pragma unroll
        for (int k = N - 1; k >= 2; --k) a[k] = bperm(src4, a[k - 1]);
        a[0] = bperm(src4, a[0]);
        a[1] = t1;
      }
      float xl = v[N - 1];
#pragma unroll
      for (int k = N - 1; k >= 2; --k) v[k] = v[k - 1];
      v[1] = xl;
      dval = bperm(src4, dnew);
    }
    ++sweep;
#pragma unroll
    for (int m = 1; m < 64; m <<= 1) offAcc += __shfl_xor(offAcc, m);
    if (sweep >= maxSweeps || offAcc < tolsq) break;   // wave-uniform
  }
}

// block = 256 threads = 4 waves; each wave owns 3 matrices (20 lanes each,
// lanes 60..63 are harmless shadows of group 2: they never write LDS/global
// and are never bpermute sources for real lanes).
// X streams from global with broadcast float2 loads (all 20 lanes of a group
// read the same address -> one line per request). The two bimap GEMVs are
// fused into one rolled row-loop with a scalar accumulator.
// launch_bounds(256,2): the backend empirically allocates floor(512/(2*w))
// VGPRs for declared w waves/EU (w=3->80, w=4->64, w=5->48, all spilling in
// the Jacobi round body); w=2 -> cap 128, which together with the in-place
// permutation (~55-60 peak live) gives zero spills.
__global__ __launch_bounds__(256, 2)
void spdnet_kernel(const float* __restrict__ X, const float* __restrict__ W1g,
                   const float* __restrict__ W2g, float* __restrict__ out,
                   int nBatch)
{
  __shared__ __align__(16) float sS[12 * 420];
  __shared__ __align__(16) float sW1t[30 * 20];   // W1 transposed: [r][i]

  const int tid = threadIdx.x;
  const int wave = tid >> 6;
  const int lane = tid & 63;
  const int grp = lane / 20;          // 0..3 (3 = shadow)
  const int l = lane - grp * 20;      // 0..19
  const int g3 = (grp < 3) ? grp : 2;
  const bool activeG = (grp < 3);
  const int wstart = blockIdx.x * 12 + wave * 3;
  const int bm = wstart + g3;
  const bool valid = activeG && (bm < nBatch);
  const int base4 = g3 * 80;          // group base lane * 4 bytes
  float* Sm = sS + (wave * 3 + g3) * 420;   // this group's scratch region

  // stage W1^T (2.4 KB): coalesced global read, scattered LDS write
  for (int t0 = tid; t0 < 600; t0 += 256) {
    int i = t0 / 30, r = t0 - i * 30;
    sW1t[r * 20 + i] = W1g[t0];
  }

  // W1 row l from global (float2: rows are only 8B-aligned)
  float w1r[30];
  {
    const float2* wr = (const float2*)(W1g + l * 30);
#pragma unroll
    for (int k2 = 0; k2 < 15; ++k2) {
      float2 q = wr[k2];
      w1r[2 * k2] = q.x; w1r[2 * k2 + 1] = q.y;
    }
  }
  __syncthreads();   // sW1t ready (only block-wide barrier in the kernel)

  // z[i] = (W1 X W1^T)[i][l] = sum_r W1t[r][i] * (X[r,:] . w1r)
  // Outer loop FORCED rolled (unroll 1) so the unroller cannot recreate the
  // round-1 pressure spike; inner loops unrolled with static register
  // indices. Two-way split accumulator halves the FMA chain.
  const int bmc = (bm < nBatch) ? bm : (nBatch - 1);   // clamp: stay in-bounds
  const float* Xm = X + (size_t)bmc * 900;
  float z[20];
#pragma unroll
  for (int i = 0; i < 20; ++i) z[i] = 0.0f;
#pragma unroll 1
  for (int r = 0; r < 30; ++r) {
    const float2* xr = (const float2*)(Xm + r * 30);   // 8B-aligned always
    float t0 = 0.0f, t1 = 0.0f;
#pragma unroll
    for (int k2 = 0; k2 < 15; ++k2) {
      float2 q = xr[k2];
      t0 = fmaf(q.x, w1r[2 * k2], t0);
      t1 = fmaf(q.y, w1r[2 * k2 + 1], t1);
    }
    float t = t0 + t1;
    const float* wc = sW1t + r * 20;    // broadcast reads (uniform address)
#pragma unroll
    for (int i = 0; i < 20; ++i) z[i] = fmaf(wc[i], t, z[i]);
  }

  // symmetrize via in-wave LDS transpose (stride 21: 20 lanes hit 20 distinct
  // banks): a[i] = 0.5*(Z[i][l] + Z[l][i]) + eps I. Bitwise symmetric since
  // fp add commutes.
  if (activeG) {
#pragma unroll
    for (int k = 0; k < 20; ++k) Sm[k * 21 + l] = z[k];   // write column l
  }
  wave_fence();
  float a[20], v[20];
#pragma unroll
  for (int i = 0; i < 20; ++i) {
    float zt = Sm[l * 21 + i];                            // read row l
    a[i] = 0.5f * (z[i] + zt) + ((i == l) ? EPSV : 0.0f);
    v[i] = (i == l) ? 1.0f : 0.0f;
  }

  jacobi_eig<20>(a, v, l, base4, valid, 2.0e-9f, 12);

  float lam1 = selN<20>(a, l);
  float gs = sqrtf(fmaxf(lam1, EPSV));

  // write V rows; then each lane grabs eigenvector column l
  if (activeG) {
#pragma unroll
    for (int k = 0; k < 20; ++k) Sm[l * 21 + k] = v[k];
  }
  wave_fence();
  float vcol[20];
#pragma unroll
  for (int r = 0; r < 20; ++r) vcol[r] = Sm[r * 21 + l];

  // b = W2 * v_l ; per-row float4 (rows are 80 B = 16B-aligned), static vcol
  // indices; uniform addresses -> L1-resident after first wave
  float b[15];
#pragma unroll
  for (int i = 0; i < 15; ++i) {
    const float4* w2r = (const float4*)(W2g + i * 20);
    float acc = 0.0f;
#pragma unroll
    for (int r4 = 0; r4 < 5; ++r4) {
      float4 q = w2r[r4];
      acc += q.x * vcol[4 * r4] + q.y * vcol[4 * r4 + 1] +
             q.z * vcol[4 * r4 + 2] + q.w * vcol[4 * r4 + 3];
    }
    b[i] = acc;
  }

  // Ut overlaps the (dead) V storage; fence orders the WAR (per-lane-disjoint
  // addresses, cross-lane overlap)
  wave_fence();
  float* Ut = Sm;                       // 15 x 20 (rows 16B-aligned)
  if (activeG) {
#pragma unroll
    for (int i = 0; i < 15; ++i) Ut[i * 20 + l] = gs * b[i];
  }
  wave_fence();

  // Y2 (padded to 16x16, dummy row/col 15 = 0): a2[r] = <Ut[r][:], Ut[l2][:]>
  const int l2 = l & 15;
  float myrow[20];
  {
    const float4* mr = (const float4*)(Ut + ((l2 < 15) ? l2 : 0) * 20);
    float msk = (l2 < 15) ? 1.0f : 0.0f;
#pragma unroll
    for (int r4 = 0; r4 < 5; ++r4) {
      float4 q = mr[r4];
      myrow[4 * r4]     = q.x * msk; myrow[4 * r4 + 1] = q.y * msk;
      myrow[4 * r4 + 2] = q.z * msk; myrow[4 * r4 + 3] = q.w * msk;
    }
  }
  float a2[16], v2[16];
  a2[15] = 0.0f;
#pragma unroll
  for (int r = 0; r < 15; ++r) {
    const float4* ur = (const float4*)(Ut + r * 20);
    float acc = 0.0f;
#pragma unroll
    for (int r4 = 0; r4 < 5; ++r4) {
      float4 q = ur[r4];
      acc += q.x * myrow[4 * r4] + q.y * myrow[4 * r4 + 1] +
             q.z * myrow[4 * r4 + 2] + q.w * myrow[4 * r4 + 3];
    }
    a2[r] = acc + ((r == l2) ? EPSV : 0.0f);
  }
#pragma unroll
  for (int k = 0; k < 16; ++k) v2[k] = (k == l2) ? 1.0f : 0.0f;

  jacobi_eig<16>(a2, v2, l2, base4, valid && (l < 16), 3.0e-10f, 12);

  float lam2 = selN<16>(a2, l2);
  float h = logf(fmaxf(lam2, EPSV));   // fused reeig+logeig: log(max(mu,eps))

  wave_fence();
  float* Wl = Sm;                       // 16 x 20 (Ut dead)
  float* hl = Sm + 400;                 // 16 (disjoint from Wl's 320)
  if (activeG && l < 16) {
#pragma unroll
    for (int k = 0; k < 16; ++k) Wl[l2 * 20 + k] = v2[k];
    hl[l2] = h;
  }
  wave_fence();

  // M[i][j] = sum_k h_k V2[i][k] V2[j][k]; lane j=l stores rows i<=j of triu
  if (valid && l < 15) {
    float wj[15], hw[15];
#pragma unroll
    for (int k = 0; k < 15; ++k) wj[k] = Wl[l * 20 + k];
#pragma unroll
    for (int k = 0; k < 15; ++k) hw[k] = hl[k] * wj[k];
    float* og = out + (size_t)bm * 120;
#pragma unroll
    for (int i = 0; i < 15; ++i) {
      const float* wr = Wl + i * 20;
      float acc = 0.0f;
#pragma unroll
      for (int k = 0; k < 15; ++k) acc += hw[k] * wr[k];
      if (i <= l) og[15 * i - (i * (i - 1)) / 2 + (l - i)] = acc;
    }
  }
}

extern "C" void kernel_launch(void* const* d_in, const int* in_sizes, int n_in,
                              void* d_out, int out_size, void* d_ws, size_t ws_size,
                              hipStream_t stream) {
  const float* X  = (const float*)d_in[0];
  const float* W1 = (const float*)d_in[1];
  const float* W2 = (const float*)d_in[2];
  float* out = (float*)d_out;
  int nBatch = in_sizes[0] / 900;
  int nBlocks = (nBatch + 11) / 12;   // 12 matrices per 256-thread block
  spdnet_kernel<<<nBlocks, 256, 0, stream>>>(X, W1, W2, out, nBatch);
}